// Round 9
// baseline (148.570 us; speedup 1.0000x reference)
//
#include <hip/hip_runtime.h>
#include <hip/hip_cooperative_groups.h>

namespace cg = cooperative_groups;

// CORN loss: logits [B, K-1] fp32, targets [B] int (1..K), out = mean loss (fp32 scalar)
// B = 4194304, K = 10 -> 9 logits/row, 37,748,736 terms = 9,437,184 float4s.
// loss(x, bt) = -log(sigmoid(bt ? x : -x) + 1e-7) ~= log(1 + exp(bt ? -x : x))
// Log batching: sum_k log(1+e^sk) = log prod_k (1+e^sk) per float4.
//
// Round-9: single cooperative kernel (one graph node). 1024 blocks x 256 thr
// = 4 blocks/CU, co-residency guaranteed by __launch_bounds__(256,4) (VGPR<=128
// -> >=4 waves/SIMD; LDS=16B). grid.sync()'s acquire-invalidate runs only after
// ALL blocks arrive (streaming done) -- avoids round-5's mid-stream L2 nuking.
// No data atomics; fixed-order reduce -> bit-deterministic across replays.

#define BATCH 4194304
#define KM1   9

constexpr int THREADS = 256;
constexpr int BLOCKS  = 1024;
constexpr int NBATCH  = 6;
constexpr int BSZ     = 6;                       // float4s per batch; 6*6=36/thread
constexpr unsigned STRIDE = BLOCKS * THREADS;    // 262144
// 1024*256*36 = 9,437,184 float4s = entire logits array, exactly.

typedef __attribute__((ext_vector_type(4))) float f32x4;

__global__ __launch_bounds__(THREADS, 4) void corn_coop_kernel(
    const float* __restrict__ logits,
    const int*   __restrict__ targets,
    float*       __restrict__ out,
    float*       __restrict__ partials) {

    const unsigned q0 = blockIdx.x * THREADS + threadIdx.x;

    float acc = 0.0f;
    #pragma unroll
    for (int b = 0; b < NBATCH; ++b) {
        // 6 coalesced loads issued up-front (lane stride 16 B -> 4 KB/wave-instr)
        f32x4 v[BSZ];
        #pragma unroll
        for (int j = 0; j < BSZ; ++j)
            v[j] = reinterpret_cast<const f32x4*>(logits)[q0 + (unsigned)(b * BSZ + j) * STRIDE];

        // Per-float4 row/rank bookkeeping (targets near-coalesced, L1-served);
        // independent of v[] -> overlaps logits-load latency.
        int rk0[BSZ], rk1[BSZ], kk0[BSZ];
        #pragma unroll
        for (int j = 0; j < BSZ; ++j) {
            const unsigned e0  = (q0 + (unsigned)(b * BSZ + j) * STRIDE) * 4u;
            const unsigned row = e0 / 9u;               // magic-mul div
            kk0[j] = (int)(e0 - 9u * row);
            const unsigned r1  = (row + 1u < BATCH) ? row + 1u : (BATCH - 1u);
            rk0[j] = targets[row] - 1;
            rk1[j] = targets[r1]  - 1;
        }

        #pragma unroll
        for (int j = 0; j < BSZ; ++j) {
            const float* f = reinterpret_cast<const float*>(&v[j]);
            float prod = 1.0f;
            #pragma unroll
            for (int c = 0; c < 4; ++c) {
                const int  k  = kk0[j] + c;
                const bool nx = (k >= 9);
                const int  kk = nx ? k - 9 : k;
                const int  rk = nx ? rk1[j] : rk0[j];
                const float x = f[c];
                const float s = (kk < rk) ? -x : x;   // bt=1 -> e^-x, bt=0 -> e^x
                prod *= 1.0f + __expf(s);             // 4 indep exps
            }
            acc += __logf(prod);                      // 1 log per 4 elements
        }
    }

    // wave (64-lane) butterfly reduce
    #pragma unroll
    for (int off = 32; off > 0; off >>= 1)
        acc += __shfl_down(acc, off, 64);

    __shared__ float smem[THREADS / 64];
    if ((threadIdx.x & 63) == 0) smem[threadIdx.x >> 6] = acc;
    __syncthreads();
    if (threadIdx.x == 0)
        partials[blockIdx.x] = smem[0] + smem[1] + smem[2] + smem[3];

    cg::this_grid().sync();   // release partials / acquire before final read

    if (blockIdx.x == 0) {                           // block-uniform branch
        float a = 0.0f;
        #pragma unroll
        for (int i = 0; i < BLOCKS / THREADS; ++i)   // 4 coalesced rounds
            a += partials[i * THREADS + threadIdx.x];
        #pragma unroll
        for (int off = 32; off > 0; off >>= 1)
            a += __shfl_down(a, off, 64);
        if ((threadIdx.x & 63) == 0) smem[threadIdx.x >> 6] = a;
        __syncthreads();
        if (threadIdx.x == 0) {
            const float inv_n = 1.0f / 37748736.0f;  // 1/(B*(K-1)), exact
            out[0] = (smem[0] + smem[1] + smem[2] + smem[3]) * inv_n;
        }
    }
}

extern "C" void kernel_launch(void* const* d_in, const int* in_sizes, int n_in,
                              void* d_out, int out_size, void* d_ws, size_t ws_size,
                              hipStream_t stream) {
    const float* logits   = (const float*)d_in[0];
    const int*   targets  = (const int*)d_in[1];
    float*       out      = (float*)d_out;
    float*       partials = (float*)d_ws;   // 1024 floats = 4 KB scratch

    void* args[] = { (void*)&logits, (void*)&targets, (void*)&out, (void*)&partials };
    hipLaunchCooperativeKernel((void*)corn_coop_kernel,
                               dim3(BLOCKS), dim3(THREADS), args, 0, stream);
}

// Round 10
// 32.535 us; speedup vs baseline: 4.5664x; 4.5664x over previous
//
#include <hip/hip_runtime.h>

// CORN loss: logits [B, K-1] fp32, targets [B] int (1..K), out = mean loss (fp32 scalar)
// B = 4194304, K = 10 -> 9 logits/row, 37,748,736 terms = 9,437,184 float4s.
// loss(x, bt) = -log(sigmoid(bt ? x : -x) + 1e-7) ~= log(1 + exp(bt ? -x : x))
// Log batching: sum_k log(1+e^sk) = log prod_k (1+e^sk) per float4
// (prod < (1+e^22)^4 < fp32 max; normal logits |x| <~ 6 -> no overflow).
//
// FINAL (round-6 structure, best measured: 32.42 us).
// Session findings:
//  - Coalesced lane-contiguous loads (16B lane stride) are mandatory: the
//    per-thread-contiguous layout cost 2x via nontemporal, ~15% without.
//  - Full-grid TLP (9216 blocks, 32 waves/CU) saturates ~6.4-6.8 TB/s read;
//    per-wave MLP depth (F4T=4 vs 8) is then irrelevant (32.4 vs 32.6 us).
//  - NO single-address atomics (125 us even relaxed: coherent-point serial
//    chain), NO ordered per-block atomics (445 us: L2 wb/inv per block),
//    NO cooperative grid.sync (158 us: low occupancy + serialized loads).
//  - ~6 us of the 32.4 is fixed graph/harness overhead (measured round 7).

#define BATCH    4194304
#define KM1      9

constexpr int THREADS = 256;
constexpr int F4_PER_THREAD = 4;
constexpr int BLOCKS = (BATCH * KM1 / 4) / (THREADS * F4_PER_THREAD);  // 9216

typedef __attribute__((ext_vector_type(4))) float f32x4;

__global__ __launch_bounds__(THREADS) void corn_partial_kernel(
    const float* __restrict__ logits,
    const int*   __restrict__ targets,
    float*       __restrict__ partials) {
    const unsigned q0 = blockIdx.x * (THREADS * F4_PER_THREAD) + threadIdx.x;

    // 4 coalesced logits loads issued up-front (lane stride 16 B -> 4 KB/wave-instr)
    f32x4 v[F4_PER_THREAD];
    #pragma unroll
    for (int j = 0; j < F4_PER_THREAD; ++j)
        v[j] = reinterpret_cast<const f32x4*>(logits)[q0 + j * THREADS];

    // Per-float4 row/rank bookkeeping (targets near-coalesced, L1/L2-served)
    int rk0[F4_PER_THREAD], rk1[F4_PER_THREAD], kk0[F4_PER_THREAD];
    #pragma unroll
    for (int j = 0; j < F4_PER_THREAD; ++j) {
        const unsigned e0  = (q0 + j * THREADS) * 4u;
        const unsigned row = e0 / 9u;                   // magic-mul div
        kk0[j] = (int)(e0 - 9u * row);
        const unsigned r1 = (row + 1u < BATCH) ? row + 1u : (BATCH - 1u);
        rk0[j] = targets[row] - 1;
        rk1[j] = targets[r1]  - 1;
    }

    float acc = 0.0f;
    #pragma unroll
    for (int j = 0; j < F4_PER_THREAD; ++j) {
        const float* f = reinterpret_cast<const float*>(&v[j]);
        float prod = 1.0f;
        #pragma unroll
        for (int c = 0; c < 4; ++c) {
            const int  k  = kk0[j] + c;
            const bool nx = (k >= 9);
            const int  kk = nx ? k - 9 : k;
            const int  rk = nx ? rk1[j] : rk0[j];
            const float x = f[c];
            const float s = (kk < rk) ? -x : x;   // bt=1 -> e^-x, bt=0 -> e^x
            prod *= 1.0f + __expf(s);             // 4 indep exps, short mul chain
        }
        acc += __logf(prod);                      // 1 log per 4 elements
    }

    // wave (64-lane) butterfly reduce
    #pragma unroll
    for (int off = 32; off > 0; off >>= 1)
        acc += __shfl_down(acc, off, 64);

    __shared__ float smem[THREADS / 64];
    if ((threadIdx.x & 63) == 0) smem[threadIdx.x >> 6] = acc;
    __syncthreads();
    if (threadIdx.x == 0)
        partials[blockIdx.x] = smem[0] + smem[1] + smem[2] + smem[3];
}

__global__ __launch_bounds__(256) void corn_final_kernel(
    const float* __restrict__ partials,
    float*       __restrict__ out) {
    float acc = 0.0f;
    #pragma unroll
    for (int i = 0; i < BLOCKS / 256; ++i)       // 36 coalesced reads/thread
        acc += partials[i * 256 + threadIdx.x];

    #pragma unroll
    for (int off = 32; off > 0; off >>= 1)
        acc += __shfl_down(acc, off, 64);

    __shared__ float smem[4];
    if ((threadIdx.x & 63) == 0) smem[threadIdx.x >> 6] = acc;
    __syncthreads();
    if (threadIdx.x == 0) {
        const float inv_n = 1.0f / 37748736.0f;  // 1/(B*(K-1)), exact
        out[0] = (smem[0] + smem[1] + smem[2] + smem[3]) * inv_n;
    }
}

extern "C" void kernel_launch(void* const* d_in, const int* in_sizes, int n_in,
                              void* d_out, int out_size, void* d_ws, size_t ws_size,
                              hipStream_t stream) {
    const float* logits   = (const float*)d_in[0];
    const int*   targets  = (const int*)d_in[1];
    float*       out      = (float*)d_out;
    float*       partials = (float*)d_ws;  // 9216 floats = 36 KB scratch

    corn_partial_kernel<<<BLOCKS, THREADS, 0, stream>>>(logits, targets, partials);
    corn_final_kernel<<<1, 256, 0, stream>>>(partials, out);
}